// Round 1
// baseline (35.203 us; speedup 1.0000x reference)
//
#include <hip/hip_runtime.h>
#include <climits>

#define LDS_RANKS 4096

// Kernel A: zero the output and initialize the per-rank tables.
__global__ void qcs_init_kernel(float* __restrict__ out, int out_size,
                                int* __restrict__ cnt, int* __restrict__ mnx, int R) {
    int tid = blockIdx.x * blockDim.x + threadIdx.x;
    int stride = gridDim.x * blockDim.x;
    int n4 = out_size >> 2;
    float4* out4 = reinterpret_cast<float4*>(out);
    float4 z = make_float4(0.f, 0.f, 0.f, 0.f);
    for (int i = tid; i < n4; i += stride) out4[i] = z;
    for (int i = (n4 << 2) + tid; i < out_size; i += stride) out[i] = 0.0f;
    for (int i = tid; i < R; i += stride) { cnt[i] = 0; mnx[i] = INT_MAX; }
}

// Kernel B: per-row rank computation; LDS-aggregated count + min-original-index
// per rank (fast path rank < 4096 covers all data here), flushed to global.
__global__ void qcs_count_kernel(const float* __restrict__ coords, int N,
                                 const int* __restrict__ pB, const int* __restrict__ pD,
                                 const int* __restrict__ pH, const int* __restrict__ pW,
                                 int* __restrict__ cnt, int* __restrict__ mnx, int R) {
    __shared__ int s_cnt[LDS_RANKS];
    __shared__ int s_mnx[LDS_RANKS];
    for (int j = threadIdx.x; j < LDS_RANKS; j += blockDim.x) {
        s_cnt[j] = 0;
        s_mnx[j] = INT_MAX;
    }
    __syncthreads();

    const int B = *pB, D = *pD, H = *pH, W = *pW;
    const int m0 = W * D * B, m1 = D * B, m2 = B;
    const int hi = H - 1;
    const int stride = gridDim.x * blockDim.x;
    const float4* c4 = reinterpret_cast<const float4*>(coords);

    for (int i = blockIdx.x * blockDim.x + threadIdx.x; i < N; i += stride) {
        float4 c = c4[i];
        // exact semantics of (coords*12).astype(int32) then clip(0, H-1)
        int i0 = min(max((int)(c.x * 12.0f), 0), hi);
        int i1 = min(max((int)(c.y * 12.0f), 0), hi);
        int i2 = min(max((int)(c.z * 12.0f), 0), hi);
        int i3 = min(max((int)(c.w * 12.0f), 0), hi);
        int rank = i0 * m0 + i1 * m1 + i2 * m2 + i3;
        if (rank < LDS_RANKS) {
            atomicAdd(&s_cnt[rank], 1);
            atomicMin(&s_mnx[rank], i);
        } else {
            atomicAdd(&cnt[rank], 1);  // generic fallback (unused for this data)
            atomicMin(&mnx[rank], i);
        }
    }
    __syncthreads();

    int lim = LDS_RANKS < R ? LDS_RANKS : R;
    for (int j = threadIdx.x; j < lim; j += blockDim.x) {
        int c = s_cnt[j];
        if (c > 0) {
            atomicAdd(&cnt[j], c);
            atomicMin(&mnx[j], s_mnx[j]);
        }
    }
}

// Kernel C: one thread per rank slot; active ranks (~408) scatter
// 0.5*count into out[geom_of_first_row][0..C).
__global__ void qcs_scatter_kernel(const float* __restrict__ coords,
                                   const int* __restrict__ cnt, const int* __restrict__ mnx,
                                   int R, int C,
                                   const int* __restrict__ pH, const int* __restrict__ pW,
                                   float* __restrict__ out) {
    int r = blockIdx.x * blockDim.x + threadIdx.x;
    if (r >= R) return;
    int count = cnt[r];
    if (count == 0) return;
    int i = mnx[r];
    const int H = *pH, W = *pW;
    const int hi = H - 1;
    float4 c = reinterpret_cast<const float4*>(coords)[i];
    int i0 = min(max((int)(c.x * 12.0f), 0), hi);
    int i1 = min(max((int)(c.y * 12.0f), 0), hi);
    int i2 = min(max((int)(c.z * 12.0f), 0), hi);
    int i3 = min(max((int)(c.w * 12.0f), 0), hi);
    int geom = i0 + i1 * W + i2 * H + i3;  // exact reference formula
    float val = 0.5f * (float)count;
    float* dst = out + (long long)geom * C;
    for (int k = 0; k < C; ++k)
        atomicAdd(&dst[k], val);  // distinct ranks may collide on geom
}

extern "C" void kernel_launch(void* const* d_in, const int* in_sizes, int n_in,
                              void* d_out, int out_size, void* d_ws, size_t ws_size,
                              hipStream_t stream) {
    // inputs: feats [N*C] f32 (never read: clipped to 0.5), coords [N*4] f32,
    // B, D, H, W as 1-element int arrays
    const float* coords = (const float*)d_in[1];
    const int* pB = (const int*)d_in[2];
    const int* pD = (const int*)d_in[3];
    const int* pH = (const int*)d_in[4];
    const int* pW = (const int*)d_in[5];

    const int N = in_sizes[1] / 4;          // 1,000,000
    const int C = in_sizes[0] / N;          // 80
    const int R = out_size / C;             // B*D*H*W = full rank space = 129,600

    int* cnt = (int*)d_ws;                  // R ints
    int* mnx = cnt + R;                     // R ints
    float* out = (float*)d_out;

    // A: zero out + init tables (41.5 MB write dominates)
    qcs_init_kernel<<<2048, 256, 0, stream>>>(out, out_size, cnt, mnx, R);

    // B: count + argmin-index per rank (16 MB coord read)
    qcs_count_kernel<<<512, 256, 0, stream>>>(coords, N, pB, pD, pH, pW, cnt, mnx, R);

    // C: scatter ~408 segments × C channels
    int blocksC = (R + 255) / 256;
    qcs_scatter_kernel<<<blocksC, 256, 0, stream>>>(coords, cnt, mnx, R, C, pH, pW, out);
}

// Round 2
// 33.397 us; speedup vs baseline: 1.0541x; 1.0541x over previous
//
#include <hip/hip_runtime.h>
#include <climits>

#define LDS_RANKS 4096
#define COUNT_BLOCKS 512
#define TOTAL_BLOCKS 2048

// K1: init per-rank tables (cnt=0, mnx=INT_MAX). ~1 MB, trivial.
__global__ void qcs_init_tables(int* __restrict__ cnt, int* __restrict__ mnx, int R) {
    int tid = blockIdx.x * blockDim.x + threadIdx.x;
    int stride = gridDim.x * blockDim.x;
    int R4 = R >> 2;
    int4* c4 = reinterpret_cast<int4*>(cnt);
    int4* m4 = reinterpret_cast<int4*>(mnx);
    int4 z = make_int4(0, 0, 0, 0);
    int4 mx = make_int4(INT_MAX, INT_MAX, INT_MAX, INT_MAX);
    for (int i = tid; i < R4; i += stride) { c4[i] = z; m4[i] = mx; }
    for (int i = (R4 << 2) + tid; i < R; i += stride) { cnt[i] = 0; mnx[i] = INT_MAX; }
}

// K2: fused. Blocks [0, COUNT_BLOCKS): per-rank count + min-original-index via
// LDS tables (all ranks < 4096 for this problem's coords), flushed to global
// with a per-block rotation to decorrelate same-address atomic chains.
// Blocks [COUNT_BLOCKS, grid): zero the 41.5 MB output with float4 stores.
// The two traffic streams (16 MB read, 42 MB write) overlap on HBM.
__global__ void qcs_fused_kernel(const float* __restrict__ coords, int N,
                                 const int* __restrict__ pB, const int* __restrict__ pD,
                                 const int* __restrict__ pH, const int* __restrict__ pW,
                                 int* __restrict__ cnt, int* __restrict__ mnx, int R,
                                 float* __restrict__ out, int out_size) {
    __shared__ int s_cnt[LDS_RANKS];
    __shared__ int s_mnx[LDS_RANKS];

    if (blockIdx.x < COUNT_BLOCKS) {
        // ---- counting path ----
        for (int j = threadIdx.x; j < LDS_RANKS; j += blockDim.x) {
            s_cnt[j] = 0;
            s_mnx[j] = INT_MAX;
        }
        __syncthreads();

        const int B = *pB, D = *pD, H = *pH, W = *pW;
        const int m0 = W * D * B, m1 = D * B, m2 = B;
        const int hi = H - 1;
        const int stride = COUNT_BLOCKS * blockDim.x;
        const float4* c4 = reinterpret_cast<const float4*>(coords);

        for (int i = blockIdx.x * blockDim.x + threadIdx.x; i < N; i += stride) {
            float4 c = c4[i];
            int i0 = min(max((int)(c.x * 12.0f), 0), hi);
            int i1 = min(max((int)(c.y * 12.0f), 0), hi);
            int i2 = min(max((int)(c.z * 12.0f), 0), hi);
            int i3 = min(max((int)(c.w * 12.0f), 0), hi);
            int rank = i0 * m0 + i1 * m1 + i2 * m2 + i3;
            if (rank < LDS_RANKS) {
                atomicAdd(&s_cnt[rank], 1);
                atomicMin(&s_mnx[rank], i);
            } else {  // generic fallback (cannot trigger for this input: rank <= 3993)
                atomicAdd(&cnt[rank], 1);
                atomicMin(&mnx[rank], i);
            }
        }
        __syncthreads();

        // rotated flush: different blocks hit a given rank at different times
        int lim = LDS_RANKS < R ? LDS_RANKS : R;
        int rot = (blockIdx.x * 64) & (LDS_RANKS - 1);
        for (int jj = threadIdx.x; jj < lim; jj += blockDim.x) {
            int j = (jj + rot) & (LDS_RANKS - 1);
            if (j >= lim) continue;
            int c = s_cnt[j];
            if (c > 0) {
                atomicAdd(&cnt[j], c);
                atomicMin(&mnx[j], s_mnx[j]);
            }
        }
    } else {
        // ---- zeroing path ----
        int zb = blockIdx.x - COUNT_BLOCKS;
        int nzb = gridDim.x - COUNT_BLOCKS;
        int tid = zb * blockDim.x + threadIdx.x;
        int stride = nzb * blockDim.x;
        int n4 = out_size >> 2;
        float4* out4 = reinterpret_cast<float4*>(out);
        float4 z = make_float4(0.f, 0.f, 0.f, 0.f);
        for (int i = tid; i < n4; i += stride) out4[i] = z;
        for (int i = (n4 << 2) + tid; i < out_size; i += stride) out[i] = 0.0f;
    }
}

// K3: one thread per rank slot; active ranks (~408) scatter 0.5*count into
// out[geom_of_first_row][0..C). atomicAdd because distinct ranks can share geom.
__global__ void qcs_scatter_kernel(const float* __restrict__ coords,
                                   const int* __restrict__ cnt, const int* __restrict__ mnx,
                                   int R, int C,
                                   const int* __restrict__ pH, const int* __restrict__ pW,
                                   float* __restrict__ out) {
    int r = blockIdx.x * blockDim.x + threadIdx.x;
    if (r >= R) return;
    int count = cnt[r];
    if (count == 0) return;
    int i = mnx[r];
    const int H = *pH, W = *pW;
    const int hi = H - 1;
    float4 c = reinterpret_cast<const float4*>(coords)[i];
    int i0 = min(max((int)(c.x * 12.0f), 0), hi);
    int i1 = min(max((int)(c.y * 12.0f), 0), hi);
    int i2 = min(max((int)(c.z * 12.0f), 0), hi);
    int i3 = min(max((int)(c.w * 12.0f), 0), hi);
    int geom = i0 + i1 * W + i2 * H + i3;  // exact reference formula
    float val = 0.5f * (float)count;
    float* dst = out + (long long)geom * C;
    for (int k = 0; k < C; ++k)
        atomicAdd(&dst[k], val);
}

extern "C" void kernel_launch(void* const* d_in, const int* in_sizes, int n_in,
                              void* d_out, int out_size, void* d_ws, size_t ws_size,
                              hipStream_t stream) {
    // inputs: feats [N*C] f32 (never read: clip(0.5,0.5) makes all values 0.5),
    // coords [N*4] f32, B, D, H, W as 1-element int arrays
    const float* coords = (const float*)d_in[1];
    const int* pB = (const int*)d_in[2];
    const int* pD = (const int*)d_in[3];
    const int* pH = (const int*)d_in[4];
    const int* pW = (const int*)d_in[5];

    const int N = in_sizes[1] / 4;          // 1,000,000
    const int C = in_sizes[0] / N;          // 80
    const int R = out_size / C;             // B*D*H*W = 129,600

    int* cnt = (int*)d_ws;                  // R ints
    int* mnx = cnt + R;                     // R ints
    float* out = (float*)d_out;

    // K1: table init (~1 MB)
    qcs_init_tables<<<256, 256, 0, stream>>>(cnt, mnx, R);

    // K2: fused zero(41.5 MB write) + count(16 MB read), overlapped on HBM
    qcs_fused_kernel<<<TOTAL_BLOCKS, 256, 0, stream>>>(coords, N, pB, pD, pH, pW,
                                                       cnt, mnx, R, out, out_size);

    // K3: scatter ~408 segments × C channels
    int blocksC = (R + 255) / 256;
    qcs_scatter_kernel<<<blocksC, 256, 0, stream>>>(coords, cnt, mnx, R, C, pH, pW, out);
}